// Round 1
// baseline (149.213 us; speedup 1.0000x reference)
//
#include <hip/hip_runtime.h>
#include <stdint.h>

namespace {
constexpr int BATCH  = 512;
constexpr int CBS    = 320;       // combined batch size
constexpr int R      = 64;        // rank
constexpr int K      = 4096;
constexpr int NADAPT = 80;
constexpr int SPLIT  = 8;         // k-split across blocks
constexpr int KS     = K / SPLIT; // 512 k per block
constexpr int TK     = 64;        // k-tile staged in LDS
constexpr int NT     = 256;       // 4 waves
constexpr int NW     = NT / 64;
constexpr int NTILES = KS / TK;   // 8

// ws layout: perm[320] ints at 0; x_bf16[512][4096] at byte 4096
constexpr size_t WS_X_OFF  = 4096;
constexpr size_t WS_NEEDED = WS_X_OFF + (size_t)BATCH * K * 2;  // ~4.2 MiB

__device__ inline uint16_t f2bf(float f) {   // RNE fp32 -> bf16
    uint32_t u = __float_as_uint(f);
    u += 0x7fffu + ((u >> 16) & 1u);
    return (uint16_t)(u >> 16);
}
__device__ inline float bf2f(uint16_t b) {
    return __uint_as_float((uint32_t)b << 16);
}
__device__ inline float bflo(uint32_t u) { return __uint_as_float(u << 16); }
__device__ inline float bfhi(uint32_t u) { return __uint_as_float(u & 0xffff0000u); }
}

// ---- pre-pass (fused): block 0 = wid-sort; blocks 1..2048 = x fp32->bf16;
//      trailing blocks zero `out` (replaces hipMemsetAsync dispatch) ----
__global__ __launch_bounds__(256)
void prep(const float* __restrict__ x, uint16_t* __restrict__ xb,
          const int* __restrict__ wids, int* __restrict__ perm,
          float* __restrict__ out, int out_size)
{
    const int bid = blockIdx.x;
    const int t   = threadIdx.x;
    if (bid == 0) {
        __shared__ int hist[NADAPT];
        __shared__ int offs[NADAPT];
        if (t < NADAPT) hist[t] = 0;
        __syncthreads();
        for (int c = t; c < CBS; c += 256) atomicAdd(&hist[wids[c]], 1);
        __syncthreads();
        if (t == 0) {
            int run = 0;
            for (int i = 0; i < NADAPT; ++i) { offs[i] = run; run += hist[i]; }
        }
        __syncthreads();
        for (int c = t; c < CBS; c += 256) {
            const int pos = atomicAdd(&offs[wids[c]], 1);
            perm[pos] = c;
        }
    } else if (bid <= BATCH * K / 1024) {          // 2048 cvt blocks
        const int i = (bid - 1) * 256 + t;         // over BATCH*K/4 float4s
        const float4 v = ((const float4*)x)[i];
        ushort4 o;
        o.x = f2bf(v.x); o.y = f2bf(v.y); o.z = f2bf(v.z); o.w = f2bf(v.w);
        ((ushort4*)xb)[i] = o;
    } else {                                       // zero out[]
        const int i4 = (bid - (1 + BATCH * K / 1024)) * 256 + t;
        const int e  = i4 * 4;
        if (e + 3 < out_size) {
            ((float4*)out)[i4] = make_float4(0.f, 0.f, 0.f, 0.f);
        } else {
            for (int q = e; q < out_size; ++q) out[q] = 0.f;
        }
    }
}

// ---- main: block (i,s) handles combo perm[i], k-slice s ----
// LDS layout: packed bf16 k-pairs, xs[buf][k2*R + col], col = r ^ (((k2>>1)&15)<<2).
// Staging: thread (kc=t&15, rg=t>>4) loads a 4r x 4k patch (4 x uint2 from 4 token
// rows) and writes 2 x ds_write_b128 (k2 = 2kc, 2kc+1). Compute: lane (r4,kq)
// reads 2 x ds_read_b128 per tile (k2 = wv*8+kq+4i), unpacks bf16 inline.
// Both sides are at the structural bank minimum (2 lanes per bank-quad/phase).
__global__ __launch_bounds__(NT, 8)
void lora_main(const int* __restrict__ xids,
               const int* __restrict__ wids,
               const float* __restrict__ A,
               const uint16_t* __restrict__ xb,
               const int* __restrict__ perm,
               float* __restrict__ out)
{
    __shared__ uint32_t xs[2][(TK / 2) * R];   // 2 x 8 KiB (double-buffered)
    __shared__ float red[NW * R];

    const int bid  = blockIdx.x;
    const int i0   = bid >> 3;         // sorted combo index (same-wid adjacent)
    const int s    = bid & 7;          // k-slice -> XCD (same-wid same-XCD)
    const int c    = perm[i0];
    const int t    = threadIdx.x;
    const int wv   = t >> 6;
    const int lane = t & 63;
    const int r4   = lane & 15;        // lane owns logical r = 4*r4 .. +3
    const int kq   = lane >> 4;

    const int wid = wids[c];
    const float* __restrict__ Aw = A + (size_t)wid * (K * R);

    // staging role: thread covers rows 4*rg..+3, k-chunk kc (4 k's = 2 pairs)
    const int kc = t & 15;
    const int rg = t >> 4;
    uint32_t rowoff[4];
#pragma unroll
    for (int j = 0; j < 4; ++j)
        rowoff[j] = (uint32_t)xids[c * R + 4 * rg + j] * K;
    const uint16_t* __restrict__ xbase = xb + (size_t)s * KS + kc * 4;
    const int colw = (4 * rg) ^ (kc << 2);
    const int w0i  = (2 * kc + 0) * R + colw;
    const int w1i  = (2 * kc + 1) * R + colw;

    // compute-side A base: k = 16*wv + 2*kq (+8*i), r = 4*r4
    const size_t aBase = (size_t)(s * KS + 16 * wv + 2 * kq) * R + 4 * r4;

    float4 acc = make_float4(0.f, 0.f, 0.f, 0.f);

    // stage tile 0
    {
        uint2 L0 = *(const uint2*)(xbase + rowoff[0]);
        uint2 L1 = *(const uint2*)(xbase + rowoff[1]);
        uint2 L2 = *(const uint2*)(xbase + rowoff[2]);
        uint2 L3 = *(const uint2*)(xbase + rowoff[3]);
        *(uint4*)&xs[0][w0i] = make_uint4(L0.x, L1.x, L2.x, L3.x);
        *(uint4*)&xs[0][w1i] = make_uint4(L0.y, L1.y, L2.y, L3.y);
    }

    uint2 P0, P1, P2, P3;
    for (int tile = 0; tile < NTILES; ++tile) {
        const int nt = tile + 1;
        if (nt < NTILES) {   // issue next-tile loads early; hide under compute
            const uint16_t* src = xbase + nt * TK;
            P0 = *(const uint2*)(src + rowoff[0]);
            P1 = *(const uint2*)(src + rowoff[1]);
            P2 = *(const uint2*)(src + rowoff[2]);
            P3 = *(const uint2*)(src + rowoff[3]);
        }
        __syncthreads();     // tile's writes visible; prev compute done

        // ---- compute from xs[tile&1] ----
        {
            const uint32_t* __restrict__ B = xs[tile & 1];
            const float* __restrict__ At = Aw + aBase + (size_t)tile * TK * R;
#pragma unroll
            for (int i = 0; i < 2; ++i) {
                const int k2  = wv * 8 + kq + 4 * i;
                const int col = (4 * r4) ^ (((k2 >> 1) & 15) << 2);
                const uint4 xv = *(const uint4*)&B[k2 * R + col];
                const float* Ap = At + (size_t)(8 * i) * R;
                const float4 a0 = *(const float4*)Ap;        // row k   (even)
                const float4 a1 = *(const float4*)(Ap + R);  // row k+1 (odd)
                acc.x = fmaf(bflo(xv.x), a0.x, acc.x);
                acc.x = fmaf(bfhi(xv.x), a1.x, acc.x);
                acc.y = fmaf(bflo(xv.y), a0.y, acc.y);
                acc.y = fmaf(bfhi(xv.y), a1.y, acc.y);
                acc.z = fmaf(bflo(xv.z), a0.z, acc.z);
                acc.z = fmaf(bfhi(xv.z), a1.z, acc.z);
                acc.w = fmaf(bflo(xv.w), a0.w, acc.w);
                acc.w = fmaf(bfhi(xv.w), a1.w, acc.w);
            }
        }

        if (nt < NTILES) {   // write next tile into the other buffer
            const int b = nt & 1;
            *(uint4*)&xs[b][w0i] = make_uint4(P0.x, P1.x, P2.x, P3.x);
            *(uint4*)&xs[b][w1i] = make_uint4(P0.y, P1.y, P2.y, P3.y);
        }
    }

    // ---- reduce over kq, then waves, one atomic per output element ----
#pragma unroll
    for (int m = 16; m < 64; m <<= 1) {
        acc.x += __shfl_xor(acc.x, m, 64);
        acc.y += __shfl_xor(acc.y, m, 64);
        acc.z += __shfl_xor(acc.z, m, 64);
        acc.w += __shfl_xor(acc.w, m, 64);
    }
    __syncthreads();   // xs reuse barrier not needed; protects red[] ordering
    if (kq == 0) {
        float* rd = &red[wv * R + 4 * r4];
        rd[0] = acc.x; rd[1] = acc.y; rd[2] = acc.z; rd[3] = acc.w;
    }
    __syncthreads();
    if (wv == 0) {
        float sum = red[lane] + red[R + lane] + red[2 * R + lane] + red[3 * R + lane];
        atomicAdd(&out[c * R + lane], sum);
    }
}

// ---- fallback (ws too small): R2 kernel, fp32 x from global, no perm ----
__global__ __launch_bounds__(NT)
void lora_fallback(const float* __restrict__ x,
                   const int*   __restrict__ xids,
                   const int*   __restrict__ wids,
                   const float* __restrict__ A,
                   float*       __restrict__ out)
{
    __shared__ float xsf[TK * R];
    __shared__ float red[NW * R];
    const int bid  = blockIdx.x;
    const int c    = bid >> 3;
    const int s    = bid & 7;
    const int t    = threadIdx.x;
    const int wave = t >> 6;
    const int lane = t & 63;
    const int r4   = lane & 15;
    const int kq   = lane >> 4;
    const int wid  = wids[c];
    const float* __restrict__ Aw = A + (size_t)wid * (K * R);
    const int rw  = t >> 2;
    const int jq  = t & 3;
    const int tok = xids[c * R + rw];
    const float* __restrict__ xrow = x + (size_t)tok * K + s * KS + jq * 16;
    float4 acc = make_float4(0.f, 0.f, 0.f, 0.f);
    float4 pv[4];
    {
        const float4* src = (const float4*)xrow;
#pragma unroll
        for (int ii = 0; ii < 4; ++ii) pv[ii] = src[ii];
    }
    for (int tile = 0; tile < NTILES; ++tile) {
#pragma unroll
        for (int ii = 0; ii < 4; ++ii) {
            const int kk = jq * 16 + ii * 4;
            xsf[(kk + 0) * R + rw] = pv[ii].x;
            xsf[(kk + 1) * R + rw] = pv[ii].y;
            xsf[(kk + 2) * R + rw] = pv[ii].z;
            xsf[(kk + 3) * R + rw] = pv[ii].w;
        }
        __syncthreads();
        if (tile + 1 < NTILES) {
            const float4* src = (const float4*)(xrow + (tile + 1) * TK);
#pragma unroll
            for (int ii = 0; ii < 4; ++ii) pv[ii] = src[ii];
        }
        const int kw = wave * 16 + kq;
        const float* __restrict__ Ap =
            Aw + (size_t)(s * KS + tile * TK + kw) * R + 4 * r4;
#pragma unroll
        for (int i = 0; i < 4; ++i) {
            float4 av = *(const float4*)(Ap + (size_t)(4 * i) * R);
            float4 xv = *(const float4*)(&xsf[(kw + 4 * i) * R + 4 * r4]);
            acc.x = fmaf(xv.x, av.x, acc.x);
            acc.y = fmaf(xv.y, av.y, acc.y);
            acc.z = fmaf(xv.z, av.z, acc.z);
            acc.w = fmaf(xv.w, av.w, acc.w);
        }
        __syncthreads();
    }
#pragma unroll
    for (int m = 16; m < 64; m <<= 1) {
        acc.x += __shfl_xor(acc.x, m, 64);
        acc.y += __shfl_xor(acc.y, m, 64);
        acc.z += __shfl_xor(acc.z, m, 64);
        acc.w += __shfl_xor(acc.w, m, 64);
    }
    if (kq == 0) {
        float* rd = &red[wave * R + 4 * r4];
        rd[0] = acc.x; rd[1] = acc.y; rd[2] = acc.z; rd[3] = acc.w;
    }
    __syncthreads();
    if (wave == 0) {
        float sum = red[lane] + red[R + lane] + red[2 * R + lane] + red[3 * R + lane];
        atomicAdd(&out[c * R + lane], sum);
    }
}

extern "C" void kernel_launch(void* const* d_in, const int* in_sizes, int n_in,
                              void* d_out, int out_size, void* d_ws, size_t ws_size,
                              hipStream_t stream)
{
    (void)in_sizes; (void)n_in;
    const float* x    = (const float*)d_in[0];
    const int*   xids = (const int*)d_in[1];
    const int*   wids = (const int*)d_in[2];
    const float* A    = (const float*)d_in[3];
    float* out        = (float*)d_out;

    if (ws_size >= WS_NEEDED) {
        int*      perm = (int*)d_ws;
        uint16_t* xbw  = (uint16_t*)((char*)d_ws + WS_X_OFF);
        const int ncvt = BATCH * K / 1024;              // 2048
        const int nz   = (out_size + 1023) / 1024;      // out-zero blocks
        hipLaunchKernelGGL(prep, dim3(1 + ncvt + nz), dim3(256), 0, stream,
                           x, xbw, wids, perm, out, out_size);
        hipLaunchKernelGGL(lora_main, dim3(CBS * SPLIT), dim3(NT), 0, stream,
                           xids, wids, A, xbw, perm, out);
    } else {
        hipMemsetAsync(out, 0, (size_t)out_size * sizeof(float), stream);
        hipLaunchKernelGGL(lora_fallback, dim3(CBS * SPLIT), dim3(NT), 0, stream,
                           x, xids, wids, A, out);
    }
}